// Round 1
// baseline (182.318 us; speedup 1.0000x reference)
//
#include <hip/hip_runtime.h>

#define IN_F   1024
#define OUT_F  64
#define INTER  32
#define BATCH  512
#define NCOL   (OUT_F * INTER)   // 2048
#define OUT_W  (IN_F + OUT_F)    // 1088

// ---------------- GEMM: M[512][2048] = x[512][1024] @ T[1024][2048] ----------------
#define BM 64
#define BN 64
#define BK 16

__global__ __launch_bounds__(256) void gemm_kernel(const float* __restrict__ x,
                                                   const float* __restrict__ T,
                                                   float* __restrict__ M) {
    // +4 float pad: keeps 16B alignment for float4 LDS reads, breaks bank conflicts
    __shared__ float As[BK][BM + 4];   // A stored transposed: As[k][row]
    __shared__ float Bs[BK][BN + 4];   // Bs[k][col]

    const int bx = blockIdx.x;           // col tile: 0..31
    const int by = blockIdx.y;           // row tile: 0..7
    const int tid = threadIdx.x;
    const int tx = tid & 15;             // 0..15 -> cols
    const int ty = tid >> 4;             // 0..15 -> rows

    const float* xblk = x + by * BM * IN_F;
    const float* Tblk = T + bx * BN;

    float acc[4][4] = {};

    for (int k0 = 0; k0 < IN_F; k0 += BK) {
        // Load A tile (64 rows x 16 k), transpose into As[k][row]
        {
            const int row = tid >> 2;            // 0..63
            const int kq  = (tid & 3) * 4;       // 0,4,8,12
            const float4 a4 = *(const float4*)(xblk + row * IN_F + k0 + kq);
            As[kq + 0][row] = a4.x;
            As[kq + 1][row] = a4.y;
            As[kq + 2][row] = a4.z;
            As[kq + 3][row] = a4.w;
        }
        // Load B tile (16 k x 64 cols)
        {
            const int kr = tid >> 4;             // 0..15
            const int cq = (tid & 15) * 4;       // 0..60
            *(float4*)&Bs[kr][cq] = *(const float4*)(Tblk + (k0 + kr) * NCOL + cq);
        }
        __syncthreads();

        #pragma unroll
        for (int k = 0; k < BK; ++k) {
            float a[4], b[4];
            *(float4*)a = *(const float4*)&As[k][ty * 4];
            *(float4*)b = *(const float4*)&Bs[k][tx * 4];
            #pragma unroll
            for (int i = 0; i < 4; ++i)
                #pragma unroll
                for (int j = 0; j < 4; ++j)
                    acc[i][j] += a[i] * b[j];
        }
        __syncthreads();
    }

    float* Cblk = M + (by * BM) * NCOL + bx * BN;
    #pragma unroll
    for (int i = 0; i < 4; ++i) {
        *(float4*)(Cblk + (ty * 4 + i) * NCOL + tx * 4) = *(const float4*)acc[i];
    }
}

// ---------------- Pairwise L1 + exp + reduce over b ----------------
// grid: (8 a-chunks, 64 o), block: 256 (4 waves).
// Lane l of every wave owns a = a0 + l, holds M[a,o,0:32] in registers.
// Wave w reduces over b in [w*128, (w+1)*128); M[b,o,:] loads are wave-uniform.
__global__ __launch_bounds__(256) void pairwise_kernel(const float* __restrict__ M,
                                                       float* __restrict__ out) {
    const int o    = blockIdx.y;
    const int a0   = blockIdx.x * 64;
    const int lane = threadIdx.x & 63;
    const int wave = threadIdx.x >> 6;
    const int a    = a0 + lane;

    float ma[INTER];
    {
        const float* pa = M + a * NCOL + o * INTER;
        #pragma unroll
        for (int k = 0; k < INTER; k += 4) {
            const float4 v = *(const float4*)(pa + k);
            ma[k] = v.x; ma[k + 1] = v.y; ma[k + 2] = v.z; ma[k + 3] = v.w;
        }
    }

    float f = 0.f;
    const float* pb = M + (wave * 128) * NCOL + o * INTER;
    for (int b = 0; b < 128; ++b) {
        float d0 = 0.f, d1 = 0.f, d2 = 0.f, d3 = 0.f;  // 4 accs break dep chain
        #pragma unroll
        for (int k = 0; k < INTER; k += 4) {
            const float4 mb = *(const float4*)(pb + k);
            d0 += fabsf(ma[k]     - mb.x);
            d1 += fabsf(ma[k + 1] - mb.y);
            d2 += fabsf(ma[k + 2] - mb.z);
            d3 += fabsf(ma[k + 3] - mb.w);
        }
        f += __expf(-((d0 + d1) + (d2 + d3)));
        pb += NCOL;
    }

    __shared__ float part[4][64];
    part[wave][lane] = f;
    __syncthreads();
    if (wave == 0) {
        const float s = part[0][lane] + part[1][lane] + part[2][lane] + part[3][lane];
        out[a * OUT_W + IN_F + o] = s;
    }
}

// ---------------- Copy x into out[:, 0:1024] ----------------
__global__ __launch_bounds__(256) void copy_x_kernel(const float* __restrict__ x,
                                                     float* __restrict__ out) {
    const int i = blockIdx.x * 256 + threadIdx.x;   // over 512*256 float4s
    const int r = i >> 8;          // row
    const int c = i & 255;         // float4 index within row
    *(float4*)(out + r * OUT_W + c * 4) = ((const float4*)(x + r * IN_F))[c];
}

extern "C" void kernel_launch(void* const* d_in, const int* in_sizes, int n_in,
                              void* d_out, int out_size, void* d_ws, size_t ws_size,
                              hipStream_t stream) {
    const float* x = (const float*)d_in[0];   // [512,1024]
    const float* T = (const float*)d_in[1];   // [1024,64,32] == [1024,2048] row-major
    float* out = (float*)d_out;               // [512,1088]
    float* M   = (float*)d_ws;                // [512,2048] scratch (4 MB)

    dim3 ggrid(NCOL / BN, BATCH / BM);        // 32 x 8
    gemm_kernel<<<ggrid, 256, 0, stream>>>(x, T, M);

    copy_x_kernel<<<(BATCH * IN_F / 4) / 256, 256, 0, stream>>>(x, out);

    dim3 pgrid(BATCH / 64, OUT_F);            // 8 x 64
    pairwise_kernel<<<pgrid, 256, 0, stream>>>(M, out);
}